// Round 4
// baseline (881.102 us; speedup 1.0000x reference)
//
#include <hip/hip_runtime.h>
#include <hip/hip_bf16.h>

#define N_NODES 585
#define DIM 256
#define BEAM 32
#define CFAN 8
#define POOL (BEAM + BEAM * CFAN)   // 288
#define BS 1024

// ---------------------------------------------------------------------------
// Kernel 1: beam search + attention. One block per batch element.
// 256 threads = 4 waves. Wave-per-node dot products, beam state in LDS.
// ---------------------------------------------------------------------------
__global__ __launch_bounds__(256) void beam_kernel(
    const float* __restrict__ tree_mem,   // [BS, N_NODES, DIM]
    const float* __restrict__ query,      // [BS, DIM]
    float* __restrict__ resp_out,         // [BS, DIM]
    float* __restrict__ att_out)          // [BS, BEAM]
{
    const int b    = blockIdx.x;
    const int tid  = threadIdx.x;
    const int w    = tid >> 6;
    const int lane = tid & 63;
    const float* tm = tree_mem + (size_t)b * (N_NODES * DIM);

    __shared__ float         pscore[POOL];
    __shared__ int           pidx[POOL];
    __shared__ unsigned char pvalid[POOL];
    __shared__ unsigned char pfin[POOL];
    __shared__ float         bscore[BEAM];
    __shared__ int           bidx[BEAM];
    __shared__ unsigned char bvalid[BEAM];
    __shared__ unsigned char bfin[BEAM];
    __shared__ float         att_s[BEAM];

    // query fragment: lane holds q[lane*4 .. lane*4+3]
    const float4 q4 = *(const float4*)(query + (size_t)b * DIM + lane * 4);

    // ---- initial pool: children of root, idx 1..32, valid for first 8 ----
    if (tid < BEAM) {
        pidx[tid]   = tid + 1;
        pvalid[tid] = (tid < CFAN) ? 1 : 0;
        pfin[tid]   = 0;
        pscore[tid] = -1e9f;
    }
    __syncthreads();

    // score nodes 1..8: wave w handles slots 2w, 2w+1
    #pragma unroll
    for (int u = 0; u < 2; ++u) {
        int k = w * 2 + u;                       // slot 0..7
        const float4 v = *(const float4*)(tm + (size_t)(k + 1) * DIM + lane * 4);
        float p = v.x * q4.x + v.y * q4.y + v.z * q4.z + v.w * q4.w;
        for (int m = 1; m < 64; m <<= 1) p += __shfl_xor(p, m);
        if (lane == 0) pscore[k] = p;
    }
    __syncthreads();

    // initial stable top-32 of 32 (rank sort; tie-break = lower index first)
    if (tid < BEAM) {
        float ms = pscore[tid];
        int r = 0;
        for (int j = 0; j < BEAM; ++j) {
            float sj = pscore[j];
            r += (sj > ms) || (sj == ms && j < tid);
        }
        bscore[r] = ms; bidx[r] = pidx[tid]; bvalid[r] = pvalid[tid]; bfin[r] = 0;
    }
    __syncthreads();

    // ---- DEPTH = 3 expansion iterations ----
    for (int it = 0; it < 3; ++it) {
        // build pool: slots 0..31 = current beam (marked finished)
        if (tid < BEAM) {
            pscore[tid] = bscore[tid];
            pidx[tid]   = bidx[tid];
            pvalid[tid] = bvalid[tid];
            pfin[tid]   = 1;
        }
        // slots 32..287 = children
        {
            int e = tid >> 3, j = tid & 7;
            int ci = bidx[e] * CFAN + 1 + j;
            unsigned char cv = (bvalid[e] && !bfin[e] && ci < N_NODES) ? 1 : 0;
            pidx[BEAM + tid]   = ci;
            pvalid[BEAM + tid] = cv;
            pfin[BEAM + tid]   = 0;
            pscore[BEAM + tid] = -1e9f;
        }
        __syncthreads();

        // score valid children. Interleaved ownership: wave w takes the
        // 8-slot batch (one beam entry's children) at slot = g*32 + w*8,
        // g = 0..7 -> balanced across waves even when only the first 64
        // child slots are valid (iteration 0). act[] is wave-uniform ->
        // execz skips dead loads+reduce.
        #pragma unroll 1
        for (int g = 0; g < 8; ++g) {
            const int slot = g * 32 + w * 8;
            float4 v[8];
            int    act[8];
            #pragma unroll
            for (int u = 0; u < 8; ++u) {
                int su = slot + u;
                act[u] = pvalid[BEAM + su];
                int ci = pidx[BEAM + su];
                ci = ci < N_NODES ? ci : (N_NODES - 1);     // never deref OOB
                if (act[u]) v[u] = *(const float4*)(tm + (size_t)ci * DIM + lane * 4);
            }
            #pragma unroll
            for (int u = 0; u < 8; ++u) {
                if (act[u]) {
                    float p = v[u].x * q4.x + v[u].y * q4.y + v[u].z * q4.z + v[u].w * q4.w;
                    for (int m = 1; m < 64; m <<= 1) p += __shfl_xor(p, m);
                    if (lane == 0) pscore[BEAM + slot + u] = p;
                }
            }
        }
        __syncthreads();

        // stable top-32 of 288 via wave-cooperative ballot rank.
        // Each lane caches 5 pool scores in registers (j = lane + 64c);
        // per slot: rank = sum_c popcount(ballot(score[j] beats score[s])).
        {
            float vj[5];
            int   jj[5];
            #pragma unroll
            for (int c = 0; c < 5; ++c) {
                int j = lane + 64 * c;
                jj[c] = j;
                vj[c] = (j < POOL) ? pscore[j] : -1e9f;
            }
            const int sBase = w * (POOL / 4);               // 72 slots per wave
            for (int si = 0; si < POOL / 4; ++si) {
                const int s = sBase + si;
                const float ms = pscore[s];
                int r = 0;
                #pragma unroll
                for (int c = 0; c < 5; ++c) {
                    bool pred = (jj[c] < POOL) &&
                                ((vj[c] > ms) || (vj[c] == ms && jj[c] < s));
                    r += __popcll(__ballot(pred));
                }
                if (r < BEAM && lane == 0) {
                    bscore[r] = ms; bidx[r] = pidx[s];
                    bvalid[r] = pvalid[s]; bfin[r] = pfin[s];
                }
            }
        }
        __syncthreads();
    }

    // ---- final masked softmax over beam (wave 0, shuffle reduce) ----
    if (w == 0) {
        // lanes 0..63 mirror entries (lane & 31): each entry counted twice,
        // harmless for max; sum gated to lane < 32.
        const int e = lane & 31;
        float sv = bvalid[e] ? bscore[e] : -99999.0f;
        float mx = sv;
        for (int m = 1; m < 64; m <<= 1) mx = fmaxf(mx, __shfl_xor(mx, m));
        float ex = __expf(sv - mx);
        float sc = (lane < 32) ? ex : 0.f;
        for (int m = 1; m < 64; m <<= 1) sc += __shfl_xor(sc, m);
        if (lane < 32) {
            float a = ex / sc;
            att_s[lane] = a;
            att_out[(size_t)b * BEAM + lane] = a;
        }
    }
    __syncthreads();

    // ---- response: resp[d] = sum_k att[k] * mem[idx[k]][d] (thread per d) ----
    float r = 0.f;
    for (int k = 0; k < BEAM; ++k) {
        int n = bidx[k];
        n = n < 0 ? 0 : (n >= N_NODES ? N_NODES - 1 : n);
        r += att_s[k] * tm[(size_t)n * DIM + tid];
    }
    resp_out[(size_t)b * DIM + tid] = r;
}

// ---------------------------------------------------------------------------
// Kernel 2/3: tiled f32 GEMM  C[M,N] = act(A[M,K] @ B[K,N] + bias)
// Tile 32 rows x 64 cols, 256 threads, 2x4 micro-tile per thread.
// CONCAT: A(r,i) = i<256 ? A0[r*256+i] : A1[r*256+i-256]
// ---------------------------------------------------------------------------
template <int K, bool CONCAT, bool RELU>
__global__ __launch_bounds__(256) void mlp_gemm(
    const float* __restrict__ A0, const float* __restrict__ A1,
    const float* __restrict__ B,  const float* __restrict__ bias,
    float* __restrict__ Cout, int N)
{
    __shared__ float At[32][68];   // +4 pad: keeps float4 alignment, kills bank conflicts
    __shared__ float Bt[64][64];

    const int tid = threadIdx.x;
    const int rowBase = blockIdx.y * 32;
    const int colBase = blockIdx.x * 64;
    const int rp = tid >> 4;      // 0..15 -> row pair
    const int cq = tid & 15;      // 0..15 -> col quad

    float acc[2][4] = {{0.f,0.f,0.f,0.f},{0.f,0.f,0.f,0.f}};

    for (int kc = 0; kc < K; kc += 64) {
        __syncthreads();
        // stage A: each thread 8 consecutive k's of one row
        {
            const int ar = tid >> 3;
            const int ac = (tid & 7) * 8;
            const int row = rowBase + ar;
            const int k = kc + ac;
            const float* src;
            if (CONCAT) {
                src = (k < 256) ? (A0 + (size_t)row * 256 + k)
                                : (A1 + (size_t)row * 256 + (k - 256));
            } else {
                src = A0 + (size_t)row * K + k;
            }
            float4 v0 = *(const float4*)(src);
            float4 v1 = *(const float4*)(src + 4);
            *(float4*)&At[ar][ac]     = v0;
            *(float4*)&At[ar][ac + 4] = v1;
        }
        // stage B: each thread 16 elements of one K-row
        {
            const int br = tid >> 2;
            const int bc = (tid & 3) * 16;
            const float* src = B + (size_t)(kc + br) * N + colBase + bc;
            #pragma unroll
            for (int j = 0; j < 4; ++j)
                *(float4*)&Bt[br][bc + j * 4] = *(const float4*)(src + j * 4);
        }
        __syncthreads();

        #pragma unroll
        for (int kk = 0; kk < 64; ++kk) {
            const float a0 = At[rp * 2 + 0][kk];
            const float a1 = At[rp * 2 + 1][kk];
            const float4 bv = *(const float4*)&Bt[kk][cq * 4];
            acc[0][0] += a0 * bv.x; acc[0][1] += a0 * bv.y;
            acc[0][2] += a0 * bv.z; acc[0][3] += a0 * bv.w;
            acc[1][0] += a1 * bv.x; acc[1][1] += a1 * bv.y;
            acc[1][2] += a1 * bv.z; acc[1][3] += a1 * bv.w;
        }
    }

    const int col = colBase + cq * 4;
    const float4 bz = *(const float4*)(bias + col);
    #pragma unroll
    for (int i = 0; i < 2; ++i) {
        const int row = rowBase + rp * 2 + i;
        float4 o;
        o.x = acc[i][0] + bz.x; o.y = acc[i][1] + bz.y;
        o.z = acc[i][2] + bz.z; o.w = acc[i][3] + bz.w;
        if (RELU) {
            o.x = fmaxf(o.x, 0.f); o.y = fmaxf(o.y, 0.f);
            o.z = fmaxf(o.z, 0.f); o.w = fmaxf(o.w, 0.f);
        }
        *(float4*)(Cout + (size_t)row * N + col) = o;
    }
}

// ---------------------------------------------------------------------------
// Kernel 4: final layer  out[r, 0..2] = h2[r,:] @ W3[512,3] + b3
// 8 rows per block, 32 lanes per row.
// ---------------------------------------------------------------------------
__global__ __launch_bounds__(256) void mlp_out_kernel(
    const float* __restrict__ h2, const float* __restrict__ W3,
    const float* __restrict__ b3, float* __restrict__ out)
{
    const int tid  = threadIdx.x;
    const int rloc = tid >> 5;          // 0..7
    const int l    = tid & 31;
    const int row  = blockIdx.x * 8 + rloc;
    const float* h = h2 + (size_t)row * 512;

    float a0 = 0.f, a1 = 0.f, a2 = 0.f;
    #pragma unroll 4
    for (int i = l * 16; i < l * 16 + 16; ++i) {
        const float hv = h[i];
        a0 += hv * W3[i * 3 + 0];
        a1 += hv * W3[i * 3 + 1];
        a2 += hv * W3[i * 3 + 2];
    }
    for (int m = 1; m < 32; m <<= 1) {
        a0 += __shfl_xor(a0, m);
        a1 += __shfl_xor(a1, m);
        a2 += __shfl_xor(a2, m);
    }
    if (l == 0) {
        out[(size_t)row * 3 + 0] = a0 + b3[0];
        out[(size_t)row * 3 + 1] = a1 + b3[1];
        out[(size_t)row * 3 + 2] = a2 + b3[2];
    }
}

// ---------------------------------------------------------------------------
extern "C" void kernel_launch(void* const* d_in, const int* in_sizes, int n_in,
                              void* d_out, int out_size, void* d_ws, size_t ws_size,
                              hipStream_t stream)
{
    const float* tree_mem = (const float*)d_in[0];
    const float* query    = (const float*)d_in[1];
    const float* W1       = (const float*)d_in[2];
    const float* b1       = (const float*)d_in[3];
    const float* W2       = (const float*)d_in[4];
    const float* b2       = (const float*)d_in[5];
    const float* W3       = (const float*)d_in[6];
    const float* b3       = (const float*)d_in[7];

    float* out  = (float*)d_out;                 // [BS, 3]
    float* resp = out + (size_t)BS * 3;          // [BS, 256]
    float* att  = resp + (size_t)BS * 256;       // [BS, 32]

    float* h1 = (float*)d_ws;                    // [BS, 256]  1 MB
    float* h2 = h1 + (size_t)BS * 256;           // [BS, 512]  2 MB

    beam_kernel<<<BS, 256, 0, stream>>>(tree_mem, query, resp, att);

    // h = [resp | query] (virtual concat): [1024,512] @ W1[512,256] -> relu -> h1
    mlp_gemm<512, true, true><<<dim3(256 / 64, BS / 32), 256, 0, stream>>>(
        resp, query, W1, b1, h1, 256);

    // h1 [1024,256] @ W2[256,512] -> relu -> h2
    mlp_gemm<256, false, true><<<dim3(512 / 64, BS / 32), 256, 0, stream>>>(
        h1, nullptr, W2, b2, h2, 512);

    // h2 [1024,512] @ W3[512,3] + b3 -> out
    mlp_out_kernel<<<BS / 8, 256, 0, stream>>>(h2, W3, b3, out);
}

// Round 5
// 814.597 us; speedup vs baseline: 1.0816x; 1.0816x over previous
//
#include <hip/hip_runtime.h>
#include <hip/hip_bf16.h>

#define N_NODES 585
#define DIM 256
#define BEAM 32
#define CFAN 8
#define POOL (BEAM + BEAM * CFAN)   // 288
#define BS 1024
#define NEG_SEL -1e9f

// ---------------------------------------------------------------------------
// Kernel 1: beam search + attention. One block per batch element.
// 256 threads = 4 waves. 16-lane-group dot products (4 nodes/wave in flight),
// beam state in LDS, ballot-rank stable top-k.
// ---------------------------------------------------------------------------
__global__ __launch_bounds__(256) void beam_kernel(
    const float* __restrict__ tree_mem,   // [BS, N_NODES, DIM]
    const float* __restrict__ query,      // [BS, DIM]
    float* __restrict__ resp_out,         // [BS, DIM]
    float* __restrict__ att_out)          // [BS, BEAM]
{
    const int b    = blockIdx.x;
    const int tid  = threadIdx.x;
    const int w    = tid >> 6;
    const int lane = tid & 63;
    const int sub  = lane & 15;           // position within 16-lane group
    const int grp  = lane >> 4;           // group 0..3 within wave
    const float* tm = tree_mem + (size_t)b * (N_NODES * DIM);

    __shared__ float         pscore[POOL];
    __shared__ int           pidx[POOL];
    __shared__ unsigned char pvalid[POOL];
    __shared__ unsigned char pfin[POOL];
    __shared__ float         bscore[BEAM];
    __shared__ int           bidx[BEAM];
    __shared__ unsigned char bvalid[BEAM];
    __shared__ unsigned char bfin[BEAM];
    __shared__ float         att_s[BEAM];

    // q fragment for 16-lane dot: lane holds q[sub*16 .. sub*16+15]
    const float* qrow = query + (size_t)b * DIM + sub * 16;
    const float4 q0 = *(const float4*)(qrow + 0);
    const float4 q1 = *(const float4*)(qrow + 4);
    const float4 q2 = *(const float4*)(qrow + 8);
    const float4 q3 = *(const float4*)(qrow + 12);

    // ---- initial pool: children of root, idx 1..32, valid for first 8 ----
    if (tid < BEAM) {
        pidx[tid]   = tid + 1;
        pvalid[tid] = (tid < CFAN) ? 1 : 0;
        pfin[tid]   = 0;
        pscore[tid] = NEG_SEL;
    }
    __syncthreads();

    // score nodes 1..8: waves 0,1 each score 4 nodes via 16-lane groups
    if (w < 2) {
        const int n = 1 + w * 4 + grp;                    // node 1..8
        const float* r = tm + (size_t)n * DIM + sub * 16;
        const float4 a0 = *(const float4*)(r + 0);
        const float4 a1 = *(const float4*)(r + 4);
        const float4 a2 = *(const float4*)(r + 8);
        const float4 a3 = *(const float4*)(r + 12);
        float p = a0.x*q0.x + a0.y*q0.y + a0.z*q0.z + a0.w*q0.w
                + a1.x*q1.x + a1.y*q1.y + a1.z*q1.z + a1.w*q1.w
                + a2.x*q2.x + a2.y*q2.y + a2.z*q2.z + a2.w*q2.w
                + a3.x*q3.x + a3.y*q3.y + a3.z*q3.z + a3.w*q3.w;
        p += __shfl_xor(p, 1); p += __shfl_xor(p, 2);
        p += __shfl_xor(p, 4); p += __shfl_xor(p, 8);
        if (sub == 0) pscore[n - 1] = p;
    }
    __syncthreads();

    // initial stable top-32 of 32 (rank sort; tie-break = lower index first)
    if (tid < BEAM) {
        float ms = pscore[tid];
        int r = 0;
        for (int j = 0; j < BEAM; ++j) {
            float sj = pscore[j];
            r += (sj > ms) || (sj == ms && j < tid);
        }
        bscore[r] = ms; bidx[r] = pidx[tid]; bvalid[r] = pvalid[tid]; bfin[r] = 0;
    }
    __syncthreads();

    // ---- DEPTH = 3 expansion iterations ----
    for (int it = 0; it < 3; ++it) {
        // build pool: slots 0..31 = current beam (marked finished)
        if (tid < BEAM) {
            pscore[tid] = bscore[tid];
            pidx[tid]   = bidx[tid];
            pvalid[tid] = bvalid[tid];
            pfin[tid]   = 1;
        }
        // slots 32..287 = children
        {
            int e = tid >> 3, j = tid & 7;
            int ci = bidx[e] * CFAN + 1 + j;
            unsigned char cv = (bvalid[e] && !bfin[e] && ci < N_NODES) ? 1 : 0;
            pidx[BEAM + tid]   = ci;
            pvalid[BEAM + tid] = cv;
            pfin[BEAM + tid]   = 0;
            pscore[BEAM + tid] = NEG_SEL;
        }
        __syncthreads();

        // score valid children. Batch = one beam entry's 8 children (validity
        // is batch-uniform: all 8 valid or none). Wave w takes batch at
        // slot = t*32 + w*8 (balanced). Within the wave: group grp scores
        // nodes {grp, 4+grp} of the batch; 16-lane dot, 4-step reduce.
        #pragma unroll 1
        for (int t = 0; t < 8; ++t) {
            const int slot = t * 32 + w * 8;
            if (!pvalid[BEAM + slot]) continue;           // dead batch: skip
            const int ci0 = pidx[BEAM + slot + grp];
            const int ci1 = pidx[BEAM + slot + 4 + grp];
            const float* r0 = tm + (size_t)ci0 * DIM + sub * 16;
            const float* r1 = tm + (size_t)ci1 * DIM + sub * 16;
            const float4 a0 = *(const float4*)(r0 + 0);
            const float4 a1 = *(const float4*)(r0 + 4);
            const float4 a2 = *(const float4*)(r0 + 8);
            const float4 a3 = *(const float4*)(r0 + 12);
            const float4 c0 = *(const float4*)(r1 + 0);
            const float4 c1 = *(const float4*)(r1 + 4);
            const float4 c2 = *(const float4*)(r1 + 8);
            const float4 c3 = *(const float4*)(r1 + 12);
            float p0 = a0.x*q0.x + a0.y*q0.y + a0.z*q0.z + a0.w*q0.w
                     + a1.x*q1.x + a1.y*q1.y + a1.z*q1.z + a1.w*q1.w
                     + a2.x*q2.x + a2.y*q2.y + a2.z*q2.z + a2.w*q2.w
                     + a3.x*q3.x + a3.y*q3.y + a3.z*q3.z + a3.w*q3.w;
            float p1 = c0.x*q0.x + c0.y*q0.y + c0.z*q0.z + c0.w*q0.w
                     + c1.x*q1.x + c1.y*q1.y + c1.z*q1.z + c1.w*q1.w
                     + c2.x*q2.x + c2.y*q2.y + c2.z*q2.z + c2.w*q2.w
                     + c3.x*q3.x + c3.y*q3.y + c3.z*q3.z + c3.w*q3.w;
            p0 += __shfl_xor(p0, 1); p0 += __shfl_xor(p0, 2);
            p0 += __shfl_xor(p0, 4); p0 += __shfl_xor(p0, 8);
            p1 += __shfl_xor(p1, 1); p1 += __shfl_xor(p1, 2);
            p1 += __shfl_xor(p1, 4); p1 += __shfl_xor(p1, 8);
            if (sub == 0) {
                pscore[BEAM + slot + grp]     = p0;
                pscore[BEAM + slot + 4 + grp] = p1;
            }
        }
        __syncthreads();

        // stable top-32 of 288 via wave-cooperative ballot rank.
        // Dead slots (score == NEG_SEL) can never enter the top-32 (>=32 real
        // entries always exist) -> skip them (wave-uniform branch).
        {
            float vj[5];
            int   jj[5];
            #pragma unroll
            for (int c = 0; c < 5; ++c) {
                int j = lane + 64 * c;
                jj[c] = j;
                vj[c] = (j < POOL) ? pscore[j] : NEG_SEL;
            }
            const int sBase = w * (POOL / 4);               // 72 slots per wave
            for (int si = 0; si < POOL / 4; ++si) {
                const int s = sBase + si;
                const float ms = pscore[s];
                if (ms == NEG_SEL) continue;                // dead slot
                int r = 0;
                #pragma unroll
                for (int c = 0; c < 5; ++c) {
                    bool pred = (jj[c] < POOL) &&
                                ((vj[c] > ms) || (vj[c] == ms && jj[c] < s));
                    r += __popcll(__ballot(pred));
                }
                if (r < BEAM && lane == 0) {
                    bscore[r] = ms; bidx[r] = pidx[s];
                    bvalid[r] = pvalid[s]; bfin[r] = pfin[s];
                }
            }
        }
        __syncthreads();
    }

    // ---- final masked softmax over beam (wave 0, shuffle reduce) ----
    if (w == 0) {
        const int e = lane & 31;
        float sv = bvalid[e] ? bscore[e] : -99999.0f;
        float mx = sv;
        for (int m = 1; m < 64; m <<= 1) mx = fmaxf(mx, __shfl_xor(mx, m));
        float ex = __expf(sv - mx);
        float sc = (lane < 32) ? ex : 0.f;
        for (int m = 1; m < 64; m <<= 1) sc += __shfl_xor(sc, m);
        if (lane < 32) {
            float a = ex / sc;
            att_s[lane] = a;
            att_out[(size_t)b * BEAM + lane] = a;
        }
    }
    __syncthreads();

    // ---- response: resp[d] = sum_k att[k] * mem[idx[k]][d] (thread per d) ----
    float r = 0.f;
    for (int k = 0; k < BEAM; ++k) {
        int n = bidx[k];
        n = n < 0 ? 0 : (n >= N_NODES ? N_NODES - 1 : n);
        r += att_s[k] * tm[(size_t)n * DIM + tid];
    }
    resp_out[(size_t)b * DIM + tid] = r;
}

// ---------------------------------------------------------------------------
// Kernel 2/3: tiled f32 GEMM  C[M,N] = act(A[M,K] @ B[K,N] + bias)
// Tile 32 rows x 64 cols, 256 threads, 2x4 micro-tile per thread.
// CONCAT: A(r,i) = i<256 ? A0[r*256+i] : A1[r*256+i-256]
// ---------------------------------------------------------------------------
template <int K, bool CONCAT, bool RELU>
__global__ __launch_bounds__(256) void mlp_gemm(
    const float* __restrict__ A0, const float* __restrict__ A1,
    const float* __restrict__ B,  const float* __restrict__ bias,
    float* __restrict__ Cout, int N)
{
    __shared__ float At[32][68];   // +4 pad: keeps float4 alignment, kills bank conflicts
    __shared__ float Bt[64][64];

    const int tid = threadIdx.x;
    const int rowBase = blockIdx.y * 32;
    const int colBase = blockIdx.x * 64;
    const int rp = tid >> 4;      // 0..15 -> row pair
    const int cq = tid & 15;      // 0..15 -> col quad

    float acc[2][4] = {{0.f,0.f,0.f,0.f},{0.f,0.f,0.f,0.f}};

    for (int kc = 0; kc < K; kc += 64) {
        __syncthreads();
        // stage A: each thread 8 consecutive k's of one row
        {
            const int ar = tid >> 3;
            const int ac = (tid & 7) * 8;
            const int row = rowBase + ar;
            const int k = kc + ac;
            const float* src;
            if (CONCAT) {
                src = (k < 256) ? (A0 + (size_t)row * 256 + k)
                                : (A1 + (size_t)row * 256 + (k - 256));
            } else {
                src = A0 + (size_t)row * K + k;
            }
            float4 v0 = *(const float4*)(src);
            float4 v1 = *(const float4*)(src + 4);
            *(float4*)&At[ar][ac]     = v0;
            *(float4*)&At[ar][ac + 4] = v1;
        }
        // stage B: each thread 16 elements of one K-row
        {
            const int br = tid >> 2;
            const int bc = (tid & 3) * 16;
            const float* src = B + (size_t)(kc + br) * N + colBase + bc;
            #pragma unroll
            for (int j = 0; j < 4; ++j)
                *(float4*)&Bt[br][bc + j * 4] = *(const float4*)(src + j * 4);
        }
        __syncthreads();

        #pragma unroll
        for (int kk = 0; kk < 64; ++kk) {
            const float a0 = At[rp * 2 + 0][kk];
            const float a1 = At[rp * 2 + 1][kk];
            const float4 bv = *(const float4*)&Bt[kk][cq * 4];
            acc[0][0] += a0 * bv.x; acc[0][1] += a0 * bv.y;
            acc[0][2] += a0 * bv.z; acc[0][3] += a0 * bv.w;
            acc[1][0] += a1 * bv.x; acc[1][1] += a1 * bv.y;
            acc[1][2] += a1 * bv.z; acc[1][3] += a1 * bv.w;
        }
    }

    const int col = colBase + cq * 4;
    const float4 bz = *(const float4*)(bias + col);
    #pragma unroll
    for (int i = 0; i < 2; ++i) {
        const int row = rowBase + rp * 2 + i;
        float4 o;
        o.x = acc[i][0] + bz.x; o.y = acc[i][1] + bz.y;
        o.z = acc[i][2] + bz.z; o.w = acc[i][3] + bz.w;
        if (RELU) {
            o.x = fmaxf(o.x, 0.f); o.y = fmaxf(o.y, 0.f);
            o.z = fmaxf(o.z, 0.f); o.w = fmaxf(o.w, 0.f);
        }
        *(float4*)(Cout + (size_t)row * N + col) = o;
    }
}

// ---------------------------------------------------------------------------
// Kernel 4: final layer  out[r, 0..2] = h2[r,:] @ W3[512,3] + b3
// 8 rows per block, 32 lanes per row.
// ---------------------------------------------------------------------------
__global__ __launch_bounds__(256) void mlp_out_kernel(
    const float* __restrict__ h2, const float* __restrict__ W3,
    const float* __restrict__ b3, float* __restrict__ out)
{
    const int tid  = threadIdx.x;
    const int rloc = tid >> 5;          // 0..7
    const int l    = tid & 31;
    const int row  = blockIdx.x * 8 + rloc;
    const float* h = h2 + (size_t)row * 512;

    float a0 = 0.f, a1 = 0.f, a2 = 0.f;
    #pragma unroll 4
    for (int i = l * 16; i < l * 16 + 16; ++i) {
        const float hv = h[i];
        a0 += hv * W3[i * 3 + 0];
        a1 += hv * W3[i * 3 + 1];
        a2 += hv * W3[i * 3 + 2];
    }
    for (int m = 1; m < 32; m <<= 1) {
        a0 += __shfl_xor(a0, m);
        a1 += __shfl_xor(a1, m);
        a2 += __shfl_xor(a2, m);
    }
    if (l == 0) {
        out[(size_t)row * 3 + 0] = a0 + b3[0];
        out[(size_t)row * 3 + 1] = a1 + b3[1];
        out[(size_t)row * 3 + 2] = a2 + b3[2];
    }
}

// ---------------------------------------------------------------------------
extern "C" void kernel_launch(void* const* d_in, const int* in_sizes, int n_in,
                              void* d_out, int out_size, void* d_ws, size_t ws_size,
                              hipStream_t stream)
{
    const float* tree_mem = (const float*)d_in[0];
    const float* query    = (const float*)d_in[1];
    const float* W1       = (const float*)d_in[2];
    const float* b1       = (const float*)d_in[3];
    const float* W2       = (const float*)d_in[4];
    const float* b2       = (const float*)d_in[5];
    const float* W3       = (const float*)d_in[6];
    const float* b3       = (const float*)d_in[7];

    float* out  = (float*)d_out;                 // [BS, 3]
    float* resp = out + (size_t)BS * 3;          // [BS, 256]
    float* att  = resp + (size_t)BS * 256;       // [BS, 32]

    float* h1 = (float*)d_ws;                    // [BS, 256]  1 MB
    float* h2 = h1 + (size_t)BS * 256;           // [BS, 512]  2 MB

    beam_kernel<<<BS, 256, 0, stream>>>(tree_mem, query, resp, att);

    // h = [resp | query] (virtual concat): [1024,512] @ W1[512,256] -> relu -> h1
    mlp_gemm<512, true, true><<<dim3(256 / 64, BS / 32), 256, 0, stream>>>(
        resp, query, W1, b1, h1, 256);

    // h1 [1024,256] @ W2[256,512] -> relu -> h2
    mlp_gemm<256, false, true><<<dim3(512 / 64, BS / 32), 256, 0, stream>>>(
        h1, nullptr, W2, b2, h2, 512);

    // h2 [1024,512] @ W3[512,3] + b3 -> out
    mlp_out_kernel<<<BS / 8, 256, 0, stream>>>(h2, W3, b3, out);
}